// Round 8
// baseline (29.475 us; speedup 1.0000x reference)
//
#include <hip/hip_runtime.h>

// CTC batch cost (Keras, blank=C-1). B=1024, T=256, C=128, L=48, S=97.
// One wave per batch element; lane l owns alpha[2l] (a0) / alpha[2l+1] (a1).
// Probability-domain DP; cross-lane a1[l-1] via ONE DPP wave_shr:1.
// IMMEDIATE exact 2^-e rescale every 8 steps (R6-proven numerics; stale-RS=8
// underflowed: pre-apply max ~2^-112 -> FTZ path deletion).
// Loads: one stream/lane (label col; lanes>=48 blank), 16-load bodies,
// QUAD-buffered (issued 3 bodies ~1200cy ahead), value-asm pinned.

#define TT 256
#define CC 128
#define LL 48
#define BS 16          // steps per body
#define NB (TT / BS)   // 16 bodies

template<int CTRL>
__device__ __forceinline__ float dpp_mv(float x) {
    union { float f; int i; } u, r;
    u.f = x;
    r.i = __builtin_amdgcn_update_dpp(0, u.i, CTRL, 0xF, 0xF, false); // invalid lanes -> 0
    return r.f;
}
__device__ __forceinline__ float rdlane(float x, int l) {
    union { float f; int i; } u, r;
    u.f = x;
    r.i = __builtin_amdgcn_readlane(u.i, l);
    return r.f;
}

__global__ __launch_bounds__(256) void ctc_fwd_v8(
    const float* __restrict__ y,       // [B, T, C]
    const int* __restrict__ labels,    // [B, L]
    float* __restrict__ out)           // [B]
{
    const int lane = threadIdx.x & 63;
    const int wave = threadIdx.x >> 6;
    const int b = blockIdx.x * 4 + wave;
    const float EPS = 1e-7f;

    int lab = CC - 1;                                  // lanes >= LL carry blank
    if (lane < LL) lab = labels[b * LL + lane];
    const int labprev = __shfl_up(lab, 1);             // once, outside loop
    const float csf = ((lane > 0) && (lane < LL) && (lab != labprev)) ? 1.0f : 0.0f;

    const float* p = y + (size_t)b * TT * CC + lab;    // per-lane column

    float A[BS], B[BS], C[BS], D[BS];
    float a0 = (lane == 0) ? 1.0f : 0.0f;              // uniform t=0 update -> alpha0
    float a1 = 0.0f;
    int lg = 0;                                        // accumulated log2 scale

#define ISSUE(buf, bi_) do {                                              \
    const int _t0 = (bi_) * BS;                                           \
    _Pragma("unroll")                                                     \
    for (int _j = 0; _j < BS; ++_j) {                                     \
        int _t = _t0 + _j; _t = (_t < TT) ? _t : (TT - 1); /* clamp */    \
        (buf)[_j] = p[(size_t)_t * CC];                                   \
    } } while (0)

#define PIN(buf) do {                                                     \
    _Pragma("unroll")                                                     \
    for (int _j = 0; _j < BS; ++_j)                                       \
        asm volatile("" : "+v"((buf)[_j]));  /* value pin, no mem clobber */ \
    } while (0)

#define STEP(pv) do {                                                     \
    const float _pl = (pv) + EPS;                                         \
    const float _pb = rdlane((pv), 63) + EPS;   /* blank prob (lane63) */ \
    const float _pp = dpp_mv<0x138>(a1);        /* wave_shr:1 -> a1[l-1], lane0->0 */ \
    const float _a0o = a0;                                                \
    a0 = (_a0o + _pp) * _pb;                                              \
    a1 = (a1 + _a0o + csf * _pp) * _pl;                                   \
    } while (0)

// Immediate exact rescale (R5/R6-proven): wave max via DPP butterfly, then 2^-e.
#define RESCALE do {                                                      \
    float _m = fmaxf(a0, a1);                                             \
    _m = fmaxf(_m, dpp_mv<0x111>(_m));   /* row_shr:1 */                  \
    _m = fmaxf(_m, dpp_mv<0x112>(_m));   /* row_shr:2 */                  \
    _m = fmaxf(_m, dpp_mv<0x114>(_m));   /* row_shr:4 */                  \
    _m = fmaxf(_m, dpp_mv<0x118>(_m));   /* row_shr:8 */                  \
    _m = fmaxf(_m, dpp_mv<0x142>(_m));   /* row_bcast:15 */               \
    _m = fmaxf(_m, dpp_mv<0x143>(_m));   /* row_bcast:31 -> lane63 */     \
    const float _mm = rdlane(_m, 63);                                     \
    int _e; (void)frexpf(_mm, &_e);                                       \
    a0 = ldexpf(a0, -_e);                                                 \
    a1 = ldexpf(a1, -_e);                                                 \
    lg += _e;                                                             \
    } while (0)

#define BODY(cons, dst, bi_) do {                                         \
    ISSUE(dst, (bi_) + 3);            /* loads 3 bodies (~1200cy) ahead */ \
    PIN(cons);                                                            \
    _Pragma("unroll")                                                     \
    for (int _k = 0; _k < BS; ++_k) {                                     \
        STEP((cons)[_k]);                                                 \
        if ((_k & 7) == 7) RESCALE;                                       \
    } } while (0)

    ISSUE(A, 0);
    ISSUE(B, 1);
    ISSUE(C, 2);
    for (int i = 0; i < NB; i += 4) {   // bodies 0..15; body bi lives in {A,B,C,D}[bi%4]
        BODY(A, D, i);
        BODY(B, A, i + 1);
        BODY(C, B, i + 2);
        BODY(D, C, i + 3);
    }

    // loss = -( log(alpha[95] + alpha[96]) + lg*ln2 ); true alpha = value * 2^lg
    const float v95 = rdlane(a1, 47);
    const float v96 = rdlane(a0, 48);
    if (lane == 0) {
        const float s = fmaxf(v95 + v96, 1e-37f);
        out[b] = -(__logf(s) + (float)lg * 0.69314718056f);
    }

#undef ISSUE
#undef PIN
#undef STEP
#undef RESCALE
#undef BODY
}

extern "C" void kernel_launch(void* const* d_in, const int* in_sizes, int n_in,
                              void* d_out, int out_size, void* d_ws, size_t ws_size,
                              hipStream_t stream) {
    const float* y = (const float*)d_in[0];
    const int* labels = (const int*)d_in[1];
    float* out = (float*)d_out;
    const int B = in_sizes[0] / (TT * CC);   // 1024
    ctc_fwd_v8<<<B / 4, 256, 0, stream>>>(y, labels, out);
}

// Round 9
// 28.133 us; speedup vs baseline: 1.0477x; 1.0477x over previous
//
#include <hip/hip_runtime.h>

// CTC batch cost (Keras, blank=C-1). B=1024, T=256, C=128, L=48, S=97.
// One wave per batch element; lane l owns alpha[2l] (a0) / alpha[2l+1] (a1).
// R9: STREAMING loads — each lane reads float2 (classes 2l,2l+1) => one
// coalesced 512B dwordx2 per row; label prob extracted in-register via
// 2x ds_bpermute + select (per-body GATHER phase, off the alpha chain).
// DP/rescale numerics identical to R8 (absmax 0.0 proven).

#define TT 256
#define CC 128
#define LL 48
#define BS 16          // rows per body
#define NB (TT / BS)   // 16 bodies

typedef float f32x2 __attribute__((ext_vector_type(2)));

template<int CTRL>
__device__ __forceinline__ float dpp_mv(float x) {
    union { float f; int i; } u, r;
    u.f = x;
    r.i = __builtin_amdgcn_update_dpp(0, u.i, CTRL, 0xF, 0xF, false); // invalid lanes -> 0
    return r.f;
}
__device__ __forceinline__ float rdlane(float x, int l) {
    union { float f; int i; } u, r;
    u.f = x;
    r.i = __builtin_amdgcn_readlane(u.i, l);
    return r.f;
}

__global__ __launch_bounds__(256) void ctc_fwd_v9(
    const float* __restrict__ y,       // [B, T, C]
    const int* __restrict__ labels,    // [B, L]
    float* __restrict__ out)           // [B]
{
    const int lane = threadIdx.x & 63;
    const int wave = threadIdx.x >> 6;
    const int b = blockIdx.x * 4 + wave;
    const float EPS = 1e-7f;

    int lab = CC - 1;                                  // lanes >= LL carry blank
    if (lane < LL) lab = labels[b * LL + lane];
    const int labprev = __shfl_up(lab, 1);             // once, outside loop
    const float csf = ((lane > 0) && (lane < LL) && (lab != labprev)) ? 1.0f : 0.0f;
    const int  bidx = (lab >> 1) << 2;                 // ds_bpermute byte index
    const bool odd  = (lab & 1);

    // Per-lane streaming pointer: classes [2*lane, 2*lane+1] of each row.
    const f32x2* p2 = (const f32x2*)(y + (size_t)b * TT * CC) + lane;

    f32x2 A[BS], B[BS], C[BS], D[BS];
    float a0 = (lane == 0) ? 1.0f : 0.0f;              // uniform t=0 update -> alpha0
    float a1 = 0.0f;
    int lg = 0;                                        // accumulated log2 scale

#define ISSUE(buf, bi_) do {                                              \
    _Pragma("unroll")                                                     \
    for (int _j = 0; _j < BS; ++_j)                                       \
        (buf)[_j] = p2[(size_t)((bi_) * BS + _j) * (CC / 2)];             \
    } while (0)

#define PIN(buf) do {                                                     \
    _Pragma("unroll")                                                     \
    for (int _j = 0; _j < BS; ++_j)                                       \
        asm volatile("" : "+v"((buf)[_j]));  /* value pin, no mem clobber */ \
    } while (0)

#define STEP2(plv, pbv) do {                                              \
    const float _pp = dpp_mv<0x138>(a1);        /* wave_shr:1 -> a1[l-1], lane0->0 */ \
    const float _a0o = a0;                                                \
    a0 = (_a0o + _pp) * (pbv);                                            \
    a1 = (a1 + _a0o + csf * _pp) * (plv);                                 \
    } while (0)

#define RESCALE do {                                                      \
    float _m = fmaxf(a0, a1);                                             \
    _m = fmaxf(_m, dpp_mv<0x111>(_m));   /* row_shr:1 */                  \
    _m = fmaxf(_m, dpp_mv<0x112>(_m));   /* row_shr:2 */                  \
    _m = fmaxf(_m, dpp_mv<0x114>(_m));   /* row_shr:4 */                  \
    _m = fmaxf(_m, dpp_mv<0x118>(_m));   /* row_shr:8 */                  \
    _m = fmaxf(_m, dpp_mv<0x142>(_m));   /* row_bcast:15 */               \
    _m = fmaxf(_m, dpp_mv<0x143>(_m));   /* row_bcast:31 -> lane63 */     \
    const float _mm = rdlane(_m, 63);                                     \
    int _e; (void)frexpf(_mm, &_e);                                       \
    a0 = ldexpf(a0, -_e);                                                 \
    a1 = ldexpf(a1, -_e);                                                 \
    lg += _e;                                                             \
    } while (0)

// Per body: issue next-next-next loads; pin current; GATHER (bpermute crossbar,
// independent of alpha chain); then the pure-VALU DP steps.
#define BODY(cons, dst, bi_) do {                                         \
    if ((bi_) + 3 < NB) ISSUE(dst, (bi_) + 3);                            \
    PIN(cons);                                                            \
    float _pl[BS], _pb[BS];                                               \
    _Pragma("unroll")                                                     \
    for (int _k = 0; _k < BS; ++_k) {                                     \
        const int _lo = __builtin_amdgcn_ds_bpermute(bidx, __float_as_int((cons)[_k].x)); \
        const int _hi = __builtin_amdgcn_ds_bpermute(bidx, __float_as_int((cons)[_k].y)); \
        _pl[_k] = __int_as_float(odd ? _hi : _lo) + EPS;                  \
        _pb[_k] = rdlane((cons)[_k].y, 63) + EPS;   /* class 127 */       \
    }                                                                     \
    _Pragma("unroll")                                                     \
    for (int _k = 0; _k < BS; ++_k) {                                     \
        STEP2(_pl[_k], _pb[_k]);                                          \
        if ((_k & 7) == 7) RESCALE;                                       \
    } } while (0)

    ISSUE(A, 0);
    ISSUE(B, 1);
    ISSUE(C, 2);
    BODY(A, D, 0);  BODY(B, A, 1);  BODY(C, B, 2);  BODY(D, C, 3);
    BODY(A, D, 4);  BODY(B, A, 5);  BODY(C, B, 6);  BODY(D, C, 7);
    BODY(A, D, 8);  BODY(B, A, 9);  BODY(C, B, 10); BODY(D, C, 11);
    BODY(A, D, 12); BODY(B, A, 13); BODY(C, B, 14); BODY(D, C, 15);

    // loss = -( log(alpha[95] + alpha[96]) + lg*ln2 ); true alpha = value * 2^lg
    const float v95 = rdlane(a1, 47);
    const float v96 = rdlane(a0, 48);
    if (lane == 0) {
        const float s = fmaxf(v95 + v96, 1e-37f);
        out[b] = -(__logf(s) + (float)lg * 0.69314718056f);
    }

#undef ISSUE
#undef PIN
#undef STEP2
#undef RESCALE
#undef BODY
}

extern "C" void kernel_launch(void* const* d_in, const int* in_sizes, int n_in,
                              void* d_out, int out_size, void* d_ws, size_t ws_size,
                              hipStream_t stream) {
    const float* y = (const float*)d_in[0];
    const int* labels = (const int*)d_in[1];
    float* out = (float*)d_out;
    const int B = in_sizes[0] / (TT * CC);   // 1024
    ctc_fwd_v9<<<B / 4, 256, 0, stream>>>(y, labels, out);
}

// Round 10
// 26.745 us; speedup vs baseline: 1.1021x; 1.0519x over previous
//
#include <hip/hip_runtime.h>

// CTC batch cost (Keras, blank=C-1). B=1024, T=256, C=128, L=48, S=97.
// R10: producer/consumer wave split. One block = 1 batch element = 2 waves.
//   wave1 (producer): streams rows coalesced (f32x2/lane), 3 chunks in flight,
//                     ds_writes into a 4-slot LDS ring, s_barrier handshake.
//   wave0 (consumer): DP; per row reads its label prob + blank prob from LDS
//                     (ds_read, no bpermute). DP/rescale numerics = R8/R9.
// Ring safety: producer writes chunk c (slot c%4) before barrier c; by barrier
// c-1 the consumer has finished chunk c-2 (>= old occupant c-4). Proven above.

#define TT 256
#define CC 128
#define LL 48
#define CH 16          // rows per chunk
#define NC (TT / CH)   // 16 chunks

typedef float f32x2 __attribute__((ext_vector_type(2)));

template<int CTRL>
__device__ __forceinline__ float dpp_mv(float x) {
    union { float f; int i; } u, r;
    u.f = x;
    r.i = __builtin_amdgcn_update_dpp(0, u.i, CTRL, 0xF, 0xF, false); // invalid lanes -> 0
    return r.f;
}
__device__ __forceinline__ float rdlane(float x, int l) {
    union { float f; int i; } u, r;
    u.f = x;
    r.i = __builtin_amdgcn_readlane(u.i, l);
    return r.f;
}

__global__ __launch_bounds__(128) void ctc_fwd_v10(
    const float* __restrict__ y,       // [B, T, C]
    const int* __restrict__ labels,    // [B, L]
    float* __restrict__ out)           // [B]
{
    __shared__ float ring[4][CH][CC];          // 32 KB
    const int lane = threadIdx.x & 63;
    const int w = threadIdx.x >> 6;            // 0 = consumer, 1 = producer
    const int b = blockIdx.x;
    const float EPS = 1e-7f;

    if (w == 1) {
        // ---------------- producer ----------------
        const f32x2* p2 = (const f32x2*)(y + (size_t)b * TT * CC) + lane;
        f32x2 RA[CH], RB[CH], RC[CH];

#define LOADP(set, c_) do {                                               \
    _Pragma("unroll")                                                     \
    for (int _j = 0; _j < CH; ++_j)                                       \
        (set)[_j] = p2[(size_t)((c_) * CH + _j) * (CC / 2)];              \
    } while (0)

#define PITER(set, c_) do {                                               \
    float* _s = &ring[(c_) & 3][0][0];                                    \
    _Pragma("unroll")                                                     \
    for (int _j = 0; _j < CH; ++_j)                                       \
        *(f32x2*)&_s[_j * CC + 2 * lane] = (set)[_j];  /* ds_write_b64 */ \
    asm volatile("s_waitcnt lgkmcnt(0)" ::: "memory");                    \
    __builtin_amdgcn_sched_barrier(0);                                    \
    __builtin_amdgcn_s_barrier();      /* chunk c_ ready for consumer */  \
    __builtin_amdgcn_sched_barrier(0);                                    \
    if ((c_) + 3 < NC) LOADP(set, (c_) + 3);                              \
    } while (0)

        LOADP(RA, 0); LOADP(RB, 1); LOADP(RC, 2);
        PITER(RA, 0);  PITER(RB, 1);  PITER(RC, 2);
        PITER(RA, 3);  PITER(RB, 4);  PITER(RC, 5);
        PITER(RA, 6);  PITER(RB, 7);  PITER(RC, 8);
        PITER(RA, 9);  PITER(RB, 10); PITER(RC, 11);
        PITER(RA, 12); PITER(RB, 13); PITER(RC, 14);
        PITER(RA, 15);
#undef LOADP
#undef PITER
    } else {
        // ---------------- consumer ----------------
        int lab = CC - 1;                              // lanes >= LL carry blank
        if (lane < LL) lab = labels[b * LL + lane];
        const int labprev = __shfl_up(lab, 1);
        const float csf = ((lane > 0) && (lane < LL) && (lab != labprev)) ? 1.0f : 0.0f;

        float a0 = (lane == 0) ? 1.0f : 0.0f;          // uniform t=0 update -> alpha0
        float a1 = 0.0f;
        int lg = 0;

#define STEP(plv, pbv) do {                                               \
    const float _pp = dpp_mv<0x138>(a1);   /* wave_shr:1 -> a1[l-1] */    \
    const float _a0o = a0;                                                \
    a0 = (_a0o + _pp) * (pbv);                                            \
    a1 = (a1 + _a0o + csf * _pp) * (plv);                                 \
    } while (0)

#define RESCALE do {                                                      \
    float _m = fmaxf(a0, a1);                                             \
    _m = fmaxf(_m, dpp_mv<0x111>(_m));   /* row_shr:1 */                  \
    _m = fmaxf(_m, dpp_mv<0x112>(_m));   /* row_shr:2 */                  \
    _m = fmaxf(_m, dpp_mv<0x114>(_m));   /* row_shr:4 */                  \
    _m = fmaxf(_m, dpp_mv<0x118>(_m));   /* row_shr:8 */                  \
    _m = fmaxf(_m, dpp_mv<0x142>(_m));   /* row_bcast:15 */               \
    _m = fmaxf(_m, dpp_mv<0x143>(_m));   /* row_bcast:31 -> lane63 */     \
    const float _mm = rdlane(_m, 63);                                     \
    int _e; (void)frexpf(_mm, &_e);                                       \
    a0 = ldexpf(a0, -_e);                                                 \
    a1 = ldexpf(a1, -_e);                                                 \
    lg += _e;                                                             \
    } while (0)

#define CITER(c_) do {                                                    \
    __builtin_amdgcn_s_barrier();        /* chunk c_ is in LDS */         \
    __builtin_amdgcn_sched_barrier(0);                                    \
    const float* _s = &ring[(c_) & 3][0][0];                              \
    float _pl[CH], _pb[CH];                                               \
    _Pragma("unroll")                                                     \
    for (int _r = 0; _r < CH; ++_r) {                                     \
        _pl[_r] = _s[_r * CC + lab] + EPS;        /* per-lane column */   \
        _pb[_r] = _s[_r * CC + (CC - 1)] + EPS;   /* broadcast read */    \
    }                                                                     \
    _Pragma("unroll")                                                     \
    for (int _r = 0; _r < CH; ++_r) {                                     \
        STEP(_pl[_r], _pb[_r]);                                           \
        if ((_r & 7) == 7) RESCALE;                                       \
    } } while (0)

        CITER(0);  CITER(1);  CITER(2);  CITER(3);
        CITER(4);  CITER(5);  CITER(6);  CITER(7);
        CITER(8);  CITER(9);  CITER(10); CITER(11);
        CITER(12); CITER(13); CITER(14); CITER(15);

        // loss = -( log(alpha[95] + alpha[96]) + lg*ln2 )
        const float v95 = rdlane(a1, 47);
        const float v96 = rdlane(a0, 48);
        if (lane == 0) {
            const float s = fmaxf(v95 + v96, 1e-37f);
            out[b] = -(__logf(s) + (float)lg * 0.69314718056f);
        }
#undef STEP
#undef RESCALE
#undef CITER
    }
}

extern "C" void kernel_launch(void* const* d_in, const int* in_sizes, int n_in,
                              void* d_out, int out_size, void* d_ws, size_t ws_size,
                              hipStream_t stream) {
    const float* y = (const float*)d_in[0];
    const int* labels = (const int*)d_in[1];
    float* out = (float*)d_out;
    const int B = in_sizes[0] / (TT * CC);   // 1024
    ctc_fwd_v10<<<B, 128, 0, stream>>>(y, labels, out);
}